// Round 5
// baseline (227.180 us; speedup 1.0000x reference)
//
#include <hip/hip_runtime.h>

#define N_WT_     10
#define WT_LEN_   512
#define FIR_TAPS_ 31
#define N_REFL_   15
#define B_        16
#define L_        160000

constexpr int   TPB   = 256;
constexpr int   NBLK  = L_ / TPB;      // 625
constexpr float INCF  = 0.032f;        // f32(512/16000), jax weak-typed scalar
constexpr int   NG0   = L_ / 16;       // 10000 level-0 groups
constexpr int   NG1   = NG0 / 16;      // 625 level-1 groups
constexpr int   NG2   = 40;            // ceil(625/16) level-2 groups (pad 625->640)
constexpr int   NG3   = 3;             // ceil(40/16)  level-3 groups (pad 40->48)

// ---------------------------------------------------------------------------
// Kernel 1: FIR-filtered wavetables  wt[w][i] = sum_t h[t]*wtab[w][(i+t-15)%512]
// ---------------------------------------------------------------------------
__global__ void fir_kernel(const float* __restrict__ wavetables,
                           const float* __restrict__ fir_h,
                           float* __restrict__ wt_out) {
    __shared__ float s_pad[WT_LEN_ + 2 * N_REFL_];
    __shared__ float s_h[FIR_TAPS_];
    const int w = blockIdx.x;
    const int i = threadIdx.x;  // 512 threads
    if (i < FIR_TAPS_) s_h[i] = fir_h[i];
    for (int j = i; j < WT_LEN_ + 2 * N_REFL_; j += blockDim.x) {
        int src = (j + WT_LEN_ - N_REFL_) % WT_LEN_;
        s_pad[j] = wavetables[w * WT_LEN_ + src];
    }
    __syncthreads();
    float acc = 0.0f;
#pragma unroll
    for (int t = 0; t < FIR_TAPS_; ++t)
        acc = fmaf(s_h[t], s_pad[i + t], acc);
    wt_out[w * WT_LEN_ + i] = acc;
}

// ---------------------------------------------------------------------------
// Kernel 2: level-0 group sums  y[g] = seq fold of 16 f32 increments
// (increments materialized to LDS first so the mul is separately rounded)
// ---------------------------------------------------------------------------
__global__ __launch_bounds__(TPB) void ysum_kernel(
        const float* __restrict__ pitch, float* __restrict__ y) {
    __shared__ float s_x[4096];
    const int b = blockIdx.y, bx = blockIdx.x, t = threadIdx.x;
    const float* prow = pitch + (size_t)b * L_;
    const int x0 = bx * 4096;
    for (int i = t; i < 4096; i += TPB) {
        int l = x0 + i;
        s_x[i] = (l < L_) ? INCF * prow[l] : 0.0f;
    }
    __syncthreads();
    const int g = bx * 256 + t;
    if (g < NG0) {
        const float* p = s_x + (g * 16 - x0);
        float acc = 0.0f;
        for (int i = 0; i < 16; ++i) acc += p[i];  // sequential f32 fold
        y[b * NG0 + g] = acc;
    }
}

// ---------------------------------------------------------------------------
// Kernel 3: per-row hierarchical scan of y (levels 1..4, base 16, seq inner)
// Emits S1[i] = inclusive scan of y at i (i.e. cumsum of x through group i).
// ---------------------------------------------------------------------------
__global__ __launch_bounds__(TPB) void hier_kernel(
        const float* __restrict__ y, float* __restrict__ S1) {
    __shared__ float s_y[NG0];        // 40 KB
    __shared__ float s_z[NG1];        // 625
    __shared__ float s_w[NG2];        // 40
    __shared__ float s_v[NG3];        // 3
    __shared__ float s_S4[NG3];
    __shared__ float s_S3[NG2];
    __shared__ float s_S2[NG1];
    const int b = blockIdx.x, t = threadIdx.x;
    const float* yrow = y + (size_t)b * NG0;
    for (int i = t; i < NG0; i += TPB) s_y[i] = yrow[i];
    __syncthreads();
    // z[j] = fold of y[16j .. 16j+15]
    for (int j = t; j < NG1; j += TPB) {
        float acc = 0.0f;
        for (int i = 0; i < 16; ++i) acc += s_y[16 * j + i];
        s_z[j] = acc;
    }
    __syncthreads();
    // w[k] = fold of z[16k .. min(16k+15, 624)]   (pad zeros are exact no-ops)
    if (t < NG2) {
        float acc = 0.0f;
        int hi = min(16 * t + 16, NG1);
        for (int i = 16 * t; i < hi; ++i) acc += s_z[i];
        s_w[t] = acc;
    }
    __syncthreads();
    // v[m] = fold of w[16m .. min(16m+15, 39)]
    if (t < NG3) {
        float acc = 0.0f;
        int hi = min(16 * t + 16, NG2);
        for (int i = 16 * t; i < hi; ++i) acc += s_w[i];
        s_v[t] = acc;
    }
    __syncthreads();
    // S4: naive sequential scan of v (3 <= base_length -> left as naive)
    if (t == 0) {
        float run = 0.0f;
        for (int m = 0; m < NG3; ++m) { run += s_v[m]; s_S4[m] = run; }
    }
    __syncthreads();
    // S3[k] = fold w[16*(k/16) .. k] + (k>=16 ? S4[k/16 - 1] : 0)
    if (t < NG2) {
        float acc = 0.0f;
        for (int i = (t >> 4) << 4; i <= t; ++i) acc += s_w[i];
        if (t >= 16) acc = acc + s_S4[(t >> 4) - 1];
        s_S3[t] = acc;
    }
    __syncthreads();
    // S2[j] = fold z[16*(j/16) .. j] + (j>=16 ? S3[j/16 - 1] : 0)
    for (int j = t; j < NG1; j += TPB) {
        float acc = 0.0f;
        for (int i = (j >> 4) << 4; i <= j; ++i) acc += s_z[i];
        if (j >= 16) acc = acc + s_S3[(j >> 4) - 1];
        s_S2[j] = acc;
    }
    __syncthreads();
    // S1[i] = fold y[16*(i/16) .. i] + (i>=16 ? S2[i/16 - 1] : 0)
    float* S1row = S1 + (size_t)b * NG0;
    for (int i = t; i < NG0; i += TPB) {
        float acc = 0.0f;
        for (int q = (i >> 4) << 4; q <= i; ++q) acc += s_y[q];
        if (i >= 16) acc = acc + s_S2[(i >> 4) - 1];
        S1row[i] = acc;
    }
}

// ---------------------------------------------------------------------------
// Kernel 4: synth — S(l) = fold x[16*(l/16) .. l] + (g0 ? S1[g0-1] : 0),
// then subtract row-0 increment, remainder, snap, lerp, attention, envelope.
// ---------------------------------------------------------------------------
__global__ __launch_bounds__(TPB) void synth_kernel(
        const float* __restrict__ pitch,
        const float* __restrict__ envelope,
        const float* __restrict__ attention,
        const float* __restrict__ wt,
        const float* __restrict__ S1,
        float* __restrict__ out) {
    __shared__ float s_wt[N_WT_ * WT_LEN_];  // 20 KiB
    __shared__ float s_x[TPB];
    const int b = blockIdx.y, c = blockIdx.x, t = threadIdx.x;
    for (int j = t; j < N_WT_ * WT_LEN_; j += TPB) s_wt[j] = wt[j];
    const int l = c * TPB + t;
    const size_t g = (size_t)b * L_ + l;
    s_x[t] = INCF * pitch[g];                 // f32 increment, separately rounded
    __syncthreads();
    // sequential in-group-of-16 fold (block is 16-group aligned)
    float acc = 0.0f;
    for (int i = t & ~15; i <= t; ++i) acc += s_x[i];
    const int g0 = l >> 4;
    if (g0 > 0) acc = acc + S1[(size_t)b * NG0 + (g0 - 1)];  // carry add

    float idx = acc - INCF * pitch[l];   // minus increment[0] (batch row 0)
    float r = fmodf(idx, 512.0f);        // lax.rem (exact)
    if (r < 0.0f) r += 512.0f;           // jnp.remainder sign fixup
    if (512.0f - r < 1e-5f) r = 0.0f;    // the reference's snap
    float fl = floorf(r);
    float alpha = r - fl;
    int lo = (int)fl;
    int hi = (int)ceilf(r);
    if (hi >= WT_LEN_) hi -= WT_LEN_;

    const float* att = attention + g * N_WT_;
    float a0 = 0.0f;
#pragma unroll
    for (int w = 0; w < N_WT_; ++w) {
        float loV = s_wt[w * WT_LEN_ + lo];
        float hiV = s_wt[w * WT_LEN_ + hi];
        a0 += att[w] * (loV + alpha * (hiV - loV));
    }
    out[g] = a0 * envelope[g];
}

// ---------------------------------------------------------------------------
extern "C" void kernel_launch(void* const* d_in, const int* in_sizes, int n_in,
                              void* d_out, int out_size, void* d_ws, size_t ws_size,
                              hipStream_t stream) {
    const float* pitch      = (const float*)d_in[0];  // (B, L, 1)
    const float* envelope   = (const float*)d_in[1];  // (B, L, 1)
    const float* attention  = (const float*)d_in[2];  // (B, L, 10)
    const float* wavetables = (const float*)d_in[3];  // (10, 512)
    const float* fir_h      = (const float*)d_in[4];  // (31,)
    float*       out        = (float*)d_out;          // (B, L, 1)

    char*  ws = (char*)d_ws;
    float* wt = (float*)(ws);                          // 20 KiB
    float* y  = (float*)(ws + 32768);                  // 16*10000*4 = 640 KB
    float* S1 = (float*)(ws + 32768 + 655360);         // 640 KB

    fir_kernel<<<dim3(N_WT_), dim3(WT_LEN_), 0, stream>>>(wavetables, fir_h, wt);
    ysum_kernel<<<dim3(40, B_), dim3(TPB), 0, stream>>>(pitch, y);
    hier_kernel<<<dim3(B_), dim3(TPB), 0, stream>>>(y, S1);
    synth_kernel<<<dim3(NBLK, B_), dim3(TPB), 0, stream>>>(
        pitch, envelope, attention, wt, S1, out);
}

// Round 6
// 217.967 us; speedup vs baseline: 1.0423x; 1.0423x over previous
//
#include <hip/hip_runtime.h>

#define N_WT_     10
#define WT_LEN_   512
#define FIR_TAPS_ 31
#define N_REFL_   15
#define B_        16
#define L_        160000

constexpr int   TPB   = 256;
constexpr float INCF  = 0.032f;        // f32(512/16000), jax weak-typed scalar
constexpr int   NG0   = L_ / 16;       // 10000 level-0 groups (of 16 samples)
constexpr int   NG1   = NG0 / 16;      // 625 level-1 groups
constexpr int   NG2   = 40;            // ceil(625/16), pad 625->640
constexpr int   NG3   = 3;             // ceil(40/16),  pad 40->48
constexpr int   CPB   = 5;             // chunks (of 256 samples) per synth block

// ---------------------------------------------------------------------------
// Kernel 1: FIR-filtered wavetables  wt[w][i] = sum_t h[t]*wtab[w][(i+t-15)%512]
// ---------------------------------------------------------------------------
__global__ void fir_kernel(const float* __restrict__ wavetables,
                           const float* __restrict__ fir_h,
                           float* __restrict__ wt_out) {
    __shared__ float s_pad[WT_LEN_ + 2 * N_REFL_];
    __shared__ float s_h[FIR_TAPS_];
    const int w = blockIdx.x;
    const int i = threadIdx.x;  // 512 threads
    if (i < FIR_TAPS_) s_h[i] = fir_h[i];
    for (int j = i; j < WT_LEN_ + 2 * N_REFL_; j += blockDim.x) {
        int src = (j + WT_LEN_ - N_REFL_) % WT_LEN_;
        s_pad[j] = wavetables[w * WT_LEN_ + src];
    }
    __syncthreads();
    float acc = 0.0f;
#pragma unroll
    for (int t = 0; t < FIR_TAPS_; ++t)
        acc = fmaf(s_h[t], s_pad[i + t], acc);
    wt_out[w * WT_LEN_ + i] = acc;
}

// ---------------------------------------------------------------------------
// Kernel 2: level-0 group sums  y[g] = sequential f32 fold of 16 increments.
// Increments go through LDS so the INCF*pitch mul is separately rounded
// (bit-exact vs the reference lowering — do not fuse into the adds).
// ---------------------------------------------------------------------------
__global__ __launch_bounds__(TPB) void ysum_kernel(
        const float* __restrict__ pitch, float* __restrict__ y) {
    __shared__ float s_x[4096];
    const int b = blockIdx.y, bx = blockIdx.x, t = threadIdx.x;
    const float* prow = pitch + (size_t)b * L_;
    const int x0 = bx * 4096;
    for (int i = t; i < 4096; i += TPB) {
        int l = x0 + i;
        s_x[i] = (l < L_) ? INCF * prow[l] : 0.0f;
    }
    __syncthreads();
    const int g = bx * 256 + t;
    if (g < NG0) {
        const float* p = s_x + (g * 16 - x0);
        float acc = 0.0f;
        for (int i = 0; i < 16; ++i) acc += p[i];  // sequential f32 fold
        y[b * NG0 + g] = acc;
    }
}

// ---------------------------------------------------------------------------
// Kernel 3: per-row hierarchical scan (base 16, sequential inner folds).
// Running folds: the running prefix of a sequential fold is bit-identical to
// recomputing each endpoint's fold from scratch (same add sequence).
// ---------------------------------------------------------------------------
__global__ __launch_bounds__(TPB) void scan_kernel(
        const float* __restrict__ y, float* __restrict__ S1) {
    __shared__ float s_y[NG0];    // 40 KB
    __shared__ float s_S1[NG0];   // 40 KB
    __shared__ float s_z[NG1];
    __shared__ float s_S2[NG1];
    __shared__ float s_w[NG2], s_S3[NG2];
    __shared__ float s_v[NG3], s_S4[NG3];
    const int b = blockIdx.x, t = threadIdx.x;
    const float* yrow = y + (size_t)b * NG0;
    for (int i = t; i < NG0; i += TPB) s_y[i] = yrow[i];
    __syncthreads();
    // z[j] = fold of y[16j..16j+15]
    for (int j = t; j < NG1; j += TPB) {
        float a = 0.0f;
        for (int i = 0; i < 16; ++i) a += s_y[16 * j + i];
        s_z[j] = a;
    }
    __syncthreads();
    // w[k] = fold of z[16k..min(16k+16,625))   (pad zeros are exact no-ops)
    if (t < NG2) {
        float a = 0.0f;
        int hi = min(16 * t + 16, NG1);
        for (int i = 16 * t; i < hi; ++i) a += s_z[i];
        s_w[t] = a;
    }
    __syncthreads();
    // v[m] = fold of w[16m..min(16m+16,40))
    if (t < NG3) {
        float a = 0.0f;
        int hi = min(16 * t + 16, NG2);
        for (int i = 16 * t; i < hi; ++i) a += s_w[i];
        s_v[t] = a;
    }
    __syncthreads();
    // S4: naive sequential scan of v
    if (t == 0) {
        float run = 0.0f;
        for (int m = 0; m < NG3; ++m) { run += s_v[m]; s_S4[m] = run; }
    }
    __syncthreads();
    // S3[k] = fold w[16*(k/16)..k] + (k>=16 ? S4[k/16-1] : 0)
    if (t < NG2) {
        float a = 0.0f;
        for (int i = (t >> 4) << 4; i <= t; ++i) a += s_w[i];
        if (t >= 16) a = a + s_S4[(t >> 4) - 1];
        s_S3[t] = a;
    }
    __syncthreads();
    // S2 via running fold per z-group (carry added after fold, per endpoint)
    if (t < NG2) {
        float r = 0.0f;
        float carry = (t > 0) ? s_S3[t - 1] : 0.0f;
        int hi = min(16 * t + 16, NG1);
        for (int k = 16 * t; k < hi; ++k) {
            r += s_z[k];
            s_S2[k] = (t > 0) ? r + carry : r;
        }
    }
    __syncthreads();
    // S1 via running fold per y-group
    for (int j = t; j < NG1; j += TPB) {
        float r = 0.0f;
        float carry = (j > 0) ? s_S2[j - 1] : 0.0f;
        for (int k = 0; k < 16; ++k) {
            r += s_y[16 * j + k];
            s_S1[16 * j + k] = (j > 0) ? r + carry : r;
        }
    }
    __syncthreads();
    float* S1row = S1 + (size_t)b * NG0;
    for (int i = t; i < NG0; i += TPB) S1row[i] = s_S1[i];
}

// ---------------------------------------------------------------------------
// Kernel 4: synth — 5 chunks of 256 samples per block (wt staging amortized).
// S(l) = fold x[16*(l/16)..l] + S1[l/16 - 1]; then phase math, lerp, mix.
// ---------------------------------------------------------------------------
__global__ __launch_bounds__(TPB) void synth_kernel(
        const float* __restrict__ pitch,
        const float* __restrict__ envelope,
        const float* __restrict__ attention,
        const float* __restrict__ wt,
        const float* __restrict__ S1,
        float* __restrict__ out) {
    __shared__ float s_wt[N_WT_ * WT_LEN_];  // 20 KiB
    __shared__ float s_att[TPB * N_WT_];     // 10 KiB
    __shared__ float s_x[TPB];
    const int b = blockIdx.y, cb = blockIdx.x, t = threadIdx.x;

    // stage wavetables once per block, vectorized
    const float4* wt4   = (const float4*)wt;
    float4*       s_wt4 = (float4*)s_wt;
    for (int i = t; i < N_WT_ * WT_LEN_ / 4; i += TPB) s_wt4[i] = wt4[i];

    const size_t rowb = (size_t)b * L_;

    for (int cc = 0; cc < CPB; ++cc) {
        const int    l0 = (cb * CPB + cc) * TPB;
        const int    l  = l0 + t;
        const size_t g  = rowb + l;
        __syncthreads();  // first iter: covers wt staging; later: s_att/s_x reuse

        // stage this chunk's attention (2560 floats) coalesced as float4
        const float4* att4   = (const float4*)(attention + (rowb + l0) * N_WT_);
        float4*       s_att4 = (float4*)s_att;
        for (int i = t; i < TPB * N_WT_ / 4; i += TPB) s_att4[i] = att4[i];
        s_x[t] = INCF * pitch[g];  // f32 increment, separately rounded via LDS
        __syncthreads();

        // sequential in-group-of-16 fold (bit-exact association)
        float acc = 0.0f;
        for (int i = t & ~15; i <= t; ++i) acc += s_x[i];
        const int g0 = l >> 4;
        if (g0 > 0) acc = acc + S1[(size_t)b * NG0 + (g0 - 1)];  // carry add

        float idx = acc - INCF * pitch[l];   // minus increment[0] (batch row 0)
        float r = fmodf(idx, 512.0f);        // lax.rem (exact for y=512)
        if (r < 0.0f) r += 512.0f;           // jnp.remainder sign fixup
        if (512.0f - r < 1e-5f) r = 0.0f;    // the reference's snap
        float fl = floorf(r);
        float alpha = r - fl;
        int lo = (int)fl;
        int hi = (int)ceilf(r);
        if (hi >= WT_LEN_) hi -= WT_LEN_;

        const float* a = s_att + t * N_WT_;
        float a0 = 0.0f;
#pragma unroll
        for (int w = 0; w < N_WT_; ++w) {
            float loV = s_wt[w * WT_LEN_ + lo];
            float hiV = s_wt[w * WT_LEN_ + hi];
            a0 += a[w] * (loV + alpha * (hiV - loV));
        }
        out[g] = a0 * envelope[g];
    }
}

// ---------------------------------------------------------------------------
extern "C" void kernel_launch(void* const* d_in, const int* in_sizes, int n_in,
                              void* d_out, int out_size, void* d_ws, size_t ws_size,
                              hipStream_t stream) {
    const float* pitch      = (const float*)d_in[0];  // (B, L, 1)
    const float* envelope   = (const float*)d_in[1];  // (B, L, 1)
    const float* attention  = (const float*)d_in[2];  // (B, L, 10)
    const float* wavetables = (const float*)d_in[3];  // (10, 512)
    const float* fir_h      = (const float*)d_in[4];  // (31,)
    float*       out        = (float*)d_out;          // (B, L, 1)

    char*  ws = (char*)d_ws;
    float* wt = (float*)(ws);                          // 20 KiB (16B-aligned)
    float* y  = (float*)(ws + 32768);                  // 16*10000*4 = 640 KB
    float* S1 = (float*)(ws + 32768 + 655360);         // 640 KB

    fir_kernel<<<dim3(N_WT_), dim3(WT_LEN_), 0, stream>>>(wavetables, fir_h, wt);
    ysum_kernel<<<dim3(40, B_), dim3(TPB), 0, stream>>>(pitch, y);
    scan_kernel<<<dim3(B_), dim3(TPB), 0, stream>>>(y, S1);
    synth_kernel<<<dim3(L_ / (TPB * CPB), B_), dim3(TPB), 0, stream>>>(
        pitch, envelope, attention, wt, S1, out);
}

// Round 7
// 204.576 us; speedup vs baseline: 1.1105x; 1.0655x over previous
//
#include <hip/hip_runtime.h>

#define N_WT_     10
#define WT_LEN_   512
#define FIR_TAPS_ 31
#define N_REFL_   15
#define B_        16
#define L_        160000

constexpr int   TPB   = 256;
constexpr float INCF  = 0.032f;        // f32(512/16000), jax weak-typed scalar
constexpr int   NG0   = L_ / 16;       // 10000 level-0 groups (of 16 samples)
constexpr int   NG1   = NG0 / 16;      // 625 level-1 groups
constexpr int   NG2   = 40;            // ceil(625/16), pad 625->640
constexpr int   NG3   = 3;             // ceil(40/16),  pad 40->48
constexpr int   CPB   = 5;             // chunks (of 256 samples) per synth block
constexpr int   WTI   = (WT_LEN_ + 1) * N_WT_;  // 513*10 interleaved (+dup row 0)

// ---------------------------------------------------------------------------
// Kernel 1: FIR-filtered wavetables, written INTERLEAVED: wt2[i*10+w],
// with row 512 duplicating row 0 (circular hi-neighbor).
// ---------------------------------------------------------------------------
__global__ void fir_kernel(const float* __restrict__ wavetables,
                           const float* __restrict__ fir_h,
                           float* __restrict__ wt2) {
    __shared__ float s_pad[WT_LEN_ + 2 * N_REFL_];
    __shared__ float s_h[FIR_TAPS_];
    const int w = blockIdx.x;
    const int i = threadIdx.x;  // 512 threads
    if (i < FIR_TAPS_) s_h[i] = fir_h[i];
    for (int j = i; j < WT_LEN_ + 2 * N_REFL_; j += blockDim.x) {
        int src = (j + WT_LEN_ - N_REFL_) % WT_LEN_;
        s_pad[j] = wavetables[w * WT_LEN_ + src];
    }
    __syncthreads();
    float acc = 0.0f;
#pragma unroll
    for (int t = 0; t < FIR_TAPS_; ++t)
        acc = fmaf(s_h[t], s_pad[i + t], acc);
    wt2[i * N_WT_ + w] = acc;
    if (i == 0) wt2[WT_LEN_ * N_WT_ + w] = acc;  // dup row 0 at row 512
}

// ---------------------------------------------------------------------------
// Kernel 2: level-0 group sums  y[g] = sequential f32 fold of 16 increments.
// Increments materialized first so the INCF*pitch mul is separately rounded.
// ---------------------------------------------------------------------------
__global__ __launch_bounds__(TPB) void ysum_kernel(
        const float* __restrict__ pitch, float* __restrict__ y) {
    __shared__ float s_x[4096];
    const int b = blockIdx.y, bx = blockIdx.x, t = threadIdx.x;
    const float* prow = pitch + (size_t)b * L_;
    const int x0 = bx * 4096;
    for (int i = t; i < 4096; i += TPB) {
        int l = x0 + i;
        s_x[i] = (l < L_) ? INCF * prow[l] : 0.0f;
    }
    __syncthreads();
    const int g = bx * 256 + t;
    if (g < NG0) {
        const float* p = s_x + (g * 16 - x0);
        float acc = 0.0f;
        for (int i = 0; i < 16; ++i) acc += p[i];  // sequential f32 fold
        y[b * NG0 + g] = acc;
    }
}

// ---------------------------------------------------------------------------
// Kernel 3: per-row hierarchical scan (base 16, sequential inner folds),
// running folds == bit-identical to per-endpoint from-scratch folds.
// ---------------------------------------------------------------------------
__global__ __launch_bounds__(TPB) void scan_kernel(
        const float* __restrict__ y, float* __restrict__ S1) {
    __shared__ float s_y[NG0];    // 40 KB
    __shared__ float s_S1[NG0];   // 40 KB
    __shared__ float s_z[NG1];
    __shared__ float s_S2[NG1];
    __shared__ float s_w[NG2], s_S3[NG2];
    __shared__ float s_v[NG3], s_S4[NG3];
    const int b = blockIdx.x, t = threadIdx.x;
    const float* yrow = y + (size_t)b * NG0;
    for (int i = t; i < NG0; i += TPB) s_y[i] = yrow[i];
    __syncthreads();
    for (int j = t; j < NG1; j += TPB) {
        float a = 0.0f;
        for (int i = 0; i < 16; ++i) a += s_y[16 * j + i];
        s_z[j] = a;
    }
    __syncthreads();
    if (t < NG2) {
        float a = 0.0f;
        int hi = min(16 * t + 16, NG1);
        for (int i = 16 * t; i < hi; ++i) a += s_z[i];
        s_w[t] = a;
    }
    __syncthreads();
    if (t < NG3) {
        float a = 0.0f;
        int hi = min(16 * t + 16, NG2);
        for (int i = 16 * t; i < hi; ++i) a += s_w[i];
        s_v[t] = a;
    }
    __syncthreads();
    if (t == 0) {
        float run = 0.0f;
        for (int m = 0; m < NG3; ++m) { run += s_v[m]; s_S4[m] = run; }
    }
    __syncthreads();
    if (t < NG2) {
        float a = 0.0f;
        for (int i = (t >> 4) << 4; i <= t; ++i) a += s_w[i];
        if (t >= 16) a = a + s_S4[(t >> 4) - 1];
        s_S3[t] = a;
    }
    __syncthreads();
    if (t < NG2) {
        float r = 0.0f;
        float carry = (t > 0) ? s_S3[t - 1] : 0.0f;
        int hi = min(16 * t + 16, NG1);
        for (int k = 16 * t; k < hi; ++k) {
            r += s_z[k];
            s_S2[k] = (t > 0) ? r + carry : r;
        }
    }
    __syncthreads();
    for (int j = t; j < NG1; j += TPB) {
        float r = 0.0f;
        float carry = (j > 0) ? s_S2[j - 1] : 0.0f;
        for (int k = 0; k < 16; ++k) {
            r += s_y[16 * j + k];
            s_S1[16 * j + k] = (j > 0) ? r + carry : r;
        }
    }
    __syncthreads();
    float* S1row = S1 + (size_t)b * NG0;
    for (int i = t; i < NG0; i += TPB) S1row[i] = s_S1[i];
}

// ---------------------------------------------------------------------------
// Kernel 4: synth — barrier-free chunk loop. Fold via wave shuffles
// (+0.0f predicated adds are exact: all partials > 0 since pitch >= 100 Hz).
// Wavetables interleaved in LDS; attention direct from global as float2.
// ---------------------------------------------------------------------------
__global__ __launch_bounds__(TPB) void synth_kernel(
        const float* __restrict__ pitch,
        const float* __restrict__ envelope,
        const float* __restrict__ attention,
        const float* __restrict__ wt2,
        const float* __restrict__ S1,
        float* __restrict__ out) {
    __shared__ float s_wt[WTI];  // 513*10 floats = 20520 B
    const int b = blockIdx.y, cb = blockIdx.x, t = threadIdx.x;
    for (int i = t; i < WTI; i += TPB) s_wt[i] = wt2[i];
    __syncthreads();  // the only barrier

    const int lane = t & 63;
    const int r16  = lane & 15;
    const int sbase = lane & ~15;
    const size_t rowb = (size_t)b * L_;
    const float* S1row = S1 + (size_t)b * NG0;

    for (int cc = 0; cc < CPB; ++cc) {
        const int    l = (cb * CPB + cc) * TPB + t;
        const size_t g = rowb + l;

        float x = INCF * pitch[g];  // f32 increment, separately rounded
        // sequential in-group-of-16 fold via shuffles (bit-exact association)
        float acc = 0.0f;
#pragma unroll
        for (int k = 0; k < 16; ++k) {
            float v = __shfl(x, sbase + k, 64);
            acc += (k <= r16) ? v : 0.0f;
        }
        const int g0 = l >> 4;
        if (g0 > 0) acc = acc + S1row[g0 - 1];  // carry add

        float idx = acc - INCF * pitch[l];   // minus increment[0] (batch row 0)
        float r = fmodf(idx, 512.0f);        // lax.rem (exact for y=512)
        if (r < 0.0f) r += 512.0f;           // jnp.remainder sign fixup
        if (512.0f - r < 1e-5f) r = 0.0f;    // the reference's snap
        float fl = floorf(r);
        float alpha = r - fl;
        int lo = (int)fl;

        // rows lo, lo+1 = 20 contiguous floats (row 512 dups row 0)
        const float2* pw = (const float2*)(s_wt + lo * N_WT_);
        float2 q0 = pw[0], q1 = pw[1], q2 = pw[2], q3 = pw[3], q4 = pw[4];
        float2 q5 = pw[5], q6 = pw[6], q7 = pw[7], q8 = pw[8], q9 = pw[9];
        float loV[10] = {q0.x, q0.y, q1.x, q1.y, q2.x, q2.y, q3.x, q3.y, q4.x, q4.y};
        float hiV[10] = {q5.x, q5.y, q6.x, q6.y, q7.x, q7.y, q8.x, q8.y, q9.x, q9.y};

        const float2* ap = (const float2*)(attention + g * N_WT_);
        float2 a01 = ap[0], a23 = ap[1], a45 = ap[2], a67 = ap[3], a89 = ap[4];
        float a[10] = {a01.x, a01.y, a23.x, a23.y, a45.x, a45.y,
                       a67.x, a67.y, a89.x, a89.y};

        float a0 = 0.0f;
#pragma unroll
        for (int w = 0; w < N_WT_; ++w)
            a0 += a[w] * (loV[w] + alpha * (hiV[w] - loV[w]));
        out[g] = a0 * envelope[g];
    }
}

// ---------------------------------------------------------------------------
extern "C" void kernel_launch(void* const* d_in, const int* in_sizes, int n_in,
                              void* d_out, int out_size, void* d_ws, size_t ws_size,
                              hipStream_t stream) {
    const float* pitch      = (const float*)d_in[0];  // (B, L, 1)
    const float* envelope   = (const float*)d_in[1];  // (B, L, 1)
    const float* attention  = (const float*)d_in[2];  // (B, L, 10)
    const float* wavetables = (const float*)d_in[3];  // (10, 512)
    const float* fir_h      = (const float*)d_in[4];  // (31,)
    float*       out        = (float*)d_out;          // (B, L, 1)

    char*  ws  = (char*)d_ws;
    float* wt2 = (float*)(ws);                         // 20520 B (reserve 32 KiB)
    float* y   = (float*)(ws + 32768);                 // 16*10000*4 = 640 KB
    float* S1  = (float*)(ws + 32768 + 655360);        // 640 KB

    fir_kernel<<<dim3(N_WT_), dim3(WT_LEN_), 0, stream>>>(wavetables, fir_h, wt2);
    ysum_kernel<<<dim3(40, B_), dim3(TPB), 0, stream>>>(pitch, y);
    scan_kernel<<<dim3(B_), dim3(TPB), 0, stream>>>(y, S1);
    synth_kernel<<<dim3(L_ / (TPB * CPB), B_), dim3(TPB), 0, stream>>>(
        pitch, envelope, attention, wt2, S1, out);
}